// Round 2
// baseline (750.428 us; speedup 1.0000x reference)
//
#include <hip/hip_runtime.h>

#define D_   1024
#define B_   48
#define Q_   48
#define R_   36
#define RP_  38
#define DQ_  256
#define NPQ_ 1728   // B_*R_

typedef __attribute__((ext_vector_type(8))) short bf16x8;
typedef __attribute__((ext_vector_type(8))) unsigned short u16x8;
typedef __attribute__((ext_vector_type(4))) float f32x4;

static __device__ __forceinline__ unsigned short f2bf(float f) {
  union { float f; unsigned u; } v; v.f = f;
  unsigned r = v.u + 0x7fffu + ((v.u >> 16) & 1u);   // round-to-nearest-even
  return (unsigned short)(r >> 16);
}
static __device__ __forceinline__ float bf2f(unsigned short h) {
  union { unsigned u; float f; } v; v.u = ((unsigned)h) << 16; return v.f;
}
static __device__ __forceinline__ void gload_lds16(const void* g, void* s) {
  __builtin_amdgcn_global_load_lds(
      (const __attribute__((address_space(1))) unsigned int*)g,
      (__attribute__((address_space(3))) unsigned int*)s, 16, 0, 0);
}

// ---------------- k_prep: capvec, cap_repr, wdyn softmax (coalesced wave-dots) ----------
__global__ __launch_bounds__(256) void k_prep(
    const float* __restrict__ cap_embed, const float* __restrict__ Wred,
    const float* __restrict__ bred, const float* __restrict__ Wproj,
    const float* __restrict__ bproj, float* __restrict__ wpl,
    float* __restrict__ capvec)
{
  const int q = blockIdx.x, t = threadIdx.x;
  const int w = t >> 6, lane = t & 63;
  __shared__ __align__(16) float cap0[D_];
  __shared__ __align__(16) float repr[DQ_];
  __shared__ __align__(16) float logits[3072];
  __shared__ float red[4];

  float4 v = ((const float4*)(cap_embed + (size_t)q * 32 * D_))[t];  // token 0
  ((float4*)cap0)[t] = v;
  float ss = v.x*v.x + v.y*v.y + v.z*v.z + v.w*v.w;
  #pragma unroll
  for (int off = 32; off > 0; off >>= 1) ss += __shfl_down(ss, off);
  if (lane == 0) red[w] = ss;
  __syncthreads();
  float rinv = rsqrtf(red[0] + red[1] + red[2] + red[3]);
  float4 cv; cv.x = v.x*rinv; cv.y = v.y*rinv; cv.z = v.z*rinv; cv.w = v.w*rinv;
  ((float4*)(capvec + (size_t)q * D_))[t] = cv;

  // cap_repr: wave w computes outputs o = w*64 .. w*64+63, coalesced row dots
  const float4* c4 = (const float4*)cap0;
  float4 c0 = c4[lane], c1 = c4[lane+64], c2 = c4[lane+128], c3 = c4[lane+192];
  for (int oi = 0; oi < 64; oi++) {
    int o = w * 64 + oi;
    const float4* wr = (const float4*)(Wred + (size_t)o * D_);
    float4 a0 = wr[lane], a1 = wr[lane+64], a2 = wr[lane+128], a3 = wr[lane+192];
    float acc = a0.x*c0.x + a0.y*c0.y + a0.z*c0.z + a0.w*c0.w
              + a1.x*c1.x + a1.y*c1.y + a1.z*c1.z + a1.w*c1.w
              + a2.x*c2.x + a2.y*c2.y + a2.z*c2.z + a2.w*c2.w
              + a3.x*c3.x + a3.y*c3.y + a3.z*c3.z + a3.w*c3.w;
    #pragma unroll
    for (int off = 32; off > 0; off >>= 1) acc += __shfl_down(acc, off);
    if (lane == 0) repr[o] = acc + bred[o];
  }
  __syncthreads();

  // logits: wave w computes 768 outputs; each dot over 256 floats = 1 float4/lane
  float4 r4 = ((const float4*)repr)[lane];
  #pragma unroll 2
  for (int oi = 0; oi < 768; oi++) {
    int o = w * 768 + oi;
    const float4* wp = (const float4*)(Wproj + (size_t)o * DQ_);
    float4 a = wp[lane];
    float acc = a.x*r4.x + a.y*r4.y + a.z*r4.z + a.w*r4.w;
    #pragma unroll
    for (int off = 32; off > 0; off >>= 1) acc += __shfl_down(acc, off);
    if (lane == 0) logits[o] = acc + bproj[o];
  }
  __syncthreads();

  #pragma unroll
  for (int ii = 0; ii < 4; ii++) {   // softmax over K=3, store planes [q][k][c]
    int d = t * 4 + ii;
    float l0 = logits[d*3], l1 = logits[d*3+1], l2 = logits[d*3+2];
    float m = fmaxf(l0, fmaxf(l1, l2));
    float e0 = expf(l0-m), e1 = expf(l1-m), e2 = expf(l2-m);
    float inv = 1.0f / (e0 + e1 + e2);
    wpl[((size_t)q*3 + 0) * D_ + d] = e0 * inv;
    wpl[((size_t)q*3 + 1) * D_ + d] = e1 * inv;
    wpl[((size_t)q*3 + 2) * D_ + d] = e2 * inv;
  }
}

// ---------------- k_xpad: img_embed -> bf16, layout [b][rp][c] (logical, no swizzle) ----
__global__ __launch_bounds__(256) void k_xpad(const float* __restrict__ img,
                                              unsigned short* __restrict__ xpb)
{
  const int br = blockIdx.x;            // 0..48*38-1
  const int b = br / RP_, rp = br % RP_;
  const int c = threadIdx.x * 4;
  short4 o;
  if (rp == 0 || rp == RP_ - 1) { o.x = 0; o.y = 0; o.z = 0; o.w = 0; }
  else {
    float4 v = *(const float4*)&img[((size_t)b * R_ + (rp-1)) * D_ + c];
    o.x = (short)f2bf(v.x); o.y = (short)f2bf(v.y);
    o.z = (short)f2bf(v.z); o.w = (short)f2bf(v.w);
  }
  *(short4*)&xpb[(size_t)br * D_ + c] = o;
}

// ---------------- k_wcbf: Wconv fp32 -> bf16, k-group XOR swizzle per row ----------------
// physical group gp holds logical group gp ^ ((row>>1)&3) within each 32-k tile
__global__ __launch_bounds__(256) void k_wcbf(const float* __restrict__ Wconv,
                                              unsigned short* __restrict__ wcbf)
{
  const int tid = blockIdx.x * 256 + threadIdx.x;   // 131072 threads
  const int m = tid >> 7;        // row 0..1023
  const int gg = tid & 127;      // group-of-8 within row
  const int tile = gg >> 2, g = gg & 3;
  const int gl = g ^ ((m >> 1) & 3);                // logical group stored at slot g
  const float* src = Wconv + (size_t)m * D_ + tile * 32 + gl * 8;
  float4 v0 = *(const float4*)src, v1 = *(const float4*)(src + 4);
  u16x8 o;
  o[0] = f2bf(v0.x); o[1] = f2bf(v0.y); o[2] = f2bf(v0.z); o[3] = f2bf(v0.w);
  o[4] = f2bf(v1.x); o[5] = f2bf(v1.y); o[6] = f2bf(v1.z); o[7] = f2bf(v1.w);
  *(u16x8*)&wcbf[(size_t)m * D_ + tile * 32 + g * 8] = o;
}

// ---------------- k_cd: conv_dyn bf16 [ql][n=b*36+r][c], swizzled k-groups --------------
__global__ __launch_bounds__(256) void k_cd(const unsigned short* __restrict__ xpb,
    const float* __restrict__ wpl, unsigned short* __restrict__ cd, int qstart)
{
  const int ql = blockIdx.y, qg = qstart + ql;
  const int t = threadIdx.x;
  const int bloc = t >> 7;                  // 0..1
  const int b = blockIdx.x * 2 + bloc;
  const int gg = t & 127;                   // group-of-8 channels
  const int tile = gg >> 2, g = gg & 3;
  const int ch = gg * 8;

  float w0[8], w1[8], w2[8];
  {
    const float4* p0 = (const float4*)(wpl + ((size_t)qg*3 + 0)*D_ + ch);
    const float4* p1 = (const float4*)(wpl + ((size_t)qg*3 + 1)*D_ + ch);
    const float4* p2 = (const float4*)(wpl + ((size_t)qg*3 + 2)*D_ + ch);
    float4 a0 = p0[0], a1 = p0[1], b0 = p1[0], b1 = p1[1], d0 = p2[0], d1 = p2[1];
    w0[0]=a0.x; w0[1]=a0.y; w0[2]=a0.z; w0[3]=a0.w; w0[4]=a1.x; w0[5]=a1.y; w0[6]=a1.z; w0[7]=a1.w;
    w1[0]=b0.x; w1[1]=b0.y; w1[2]=b0.z; w1[3]=b0.w; w1[4]=b1.x; w1[5]=b1.y; w1[6]=b1.z; w1[7]=b1.w;
    w2[0]=d0.x; w2[1]=d0.y; w2[2]=d0.z; w2[3]=d0.w; w2[4]=d1.x; w2[5]=d1.y; w2[6]=d1.z; w2[7]=d1.w;
  }
  const unsigned short* xb = xpb + (size_t)b * RP_ * D_ + ch;
  u16x8 ra = *(const u16x8*)&xb[0];
  u16x8 rb = *(const u16x8*)&xb[D_];
  unsigned short* outb = cd + ((size_t)ql * NPQ_ + (size_t)b * R_) * D_ + tile * 32;
  const int swz0 = ((b * 36) >> 1) & 3;   // parity base; recompute per r below
  (void)swz0;
  for (int r = 0; r < R_; r++) {
    u16x8 rc = *(const u16x8*)&xb[(size_t)(r + 2) * D_];
    u16x8 o;
    #pragma unroll
    for (int i = 0; i < 8; i++) {
      float y = w0[i]*bf2f(ra[i]) + w1[i]*bf2f(rb[i]) + w2[i]*bf2f(rc[i]);
      o[i] = f2bf(y);
    }
    int gp = g ^ (((b * 36 + r) >> 1) & 3);
    *(u16x8*)&outb[(size_t)r * D_ + gp * 8] = o;
    ra = rb; rb = rc;
  }
}

// ---------------- k_gemm: Y = Wconv @ Cd_q, fused r-softmax epilogue -> imgvec ----------
#define BM_ 128
#define BN_ 144
#define BK_ 64

__global__ __launch_bounds__(256, 2) void k_gemm(
    const unsigned short* __restrict__ wcbf, const unsigned short* __restrict__ cd,
    const float* __restrict__ bconv, float* __restrict__ imgvec, int qstart)
{
  __shared__ __align__(16) unsigned char smem[37376];   // max(A 16KB + B 18KB, ep 128*73*4)
  unsigned short* As = (unsigned short*)smem;            // 16 chunks x 512 bf16
  unsigned short* Bs = (unsigned short*)(smem + 16384);  // 18 chunks x 512 bf16
  float* ep = (float*)smem;                              // [128][73] fp32 (epilogue)

  const int t = threadIdx.x;
  const int w = t >> 6, lane = t & 63;
  const int nt0 = blockIdx.x * BN_;
  const int dt0 = blockIdx.y * BM_;
  const int ql = blockIdx.z, qg = qstart + ql;

  f32x4 acc[2][9];
  #pragma unroll
  for (int mm = 0; mm < 2; mm++)
    #pragma unroll
    for (int nt = 0; nt < 9; nt++)
      acc[mm][nt] = (f32x4){0.f, 0.f, 0.f, 0.f};

  const int lrow = lane >> 2;          // 0..15 (row within 16-row chunk)
  const int lc8  = (lane & 3) * 8;     // 0,8,16,24 (phys k offset within 32-tile)
  const unsigned short* Ag = wcbf + (size_t)dt0 * D_ + lc8;
  const unsigned short* Bg = cd + ((size_t)ql * NPQ_ + nt0) * D_ + lc8;
  const int fr = lane & 15;
  // swizzled fragment offset within a 16x32 chunk (shorts):
  const int fro = fr * 32 + ((((lane >> 4) ^ ((fr >> 1) & 3))) << 3);

  for (int k0 = 0; k0 < D_; k0 += BK_) {
    #pragma unroll
    for (int jj = 0; jj < 2; jj++) {             // A: 8 row-chunks x 2 k-halves
      int j = w + jj * 4;
      #pragma unroll
      for (int h = 0; h < 2; h++)
        gload_lds16(Ag + (size_t)(j*16 + lrow) * D_ + k0 + h*32,
                    As + (j*2 + h) * 512);
    }
    for (int u = w; u < 18; u += 4) {            // B: 9 row-chunks x 2 k-halves
      int jb = u >> 1, h = u & 1;
      gload_lds16(Bg + (size_t)(jb*16 + lrow) * D_ + k0 + h*32,
                  Bs + u * 512);
    }
    __syncthreads();
    #pragma unroll
    for (int s = 0; s < 2; s++) {
      bf16x8 aF[2], bF[9];
      #pragma unroll
      for (int mm = 0; mm < 2; mm++)
        aF[mm] = *(const bf16x8*)&As[(w*4 + mm*2 + s) * 512 + fro];
      #pragma unroll
      for (int nt = 0; nt < 9; nt++)
        bF[nt] = *(const bf16x8*)&Bs[(nt*2 + s) * 512 + fro];
      #pragma unroll
      for (int mm = 0; mm < 2; mm++)
        #pragma unroll
        for (int nt = 0; nt < 9; nt++)
          acc[mm][nt] = __builtin_amdgcn_mfma_f32_16x16x32_bf16(aF[mm], bF[nt], acc[mm][nt], 0, 0, 0);
    }
    __syncthreads();
  }

  // Epilogue: softmax over r (36 cols per b), two 72-col passes, ep pitch 73.
  const int quad = lane >> 4;
  const int b0 = nt0 / R_;   // first image-batch index of this tile (4 b's per tile)
  #pragma unroll
  for (int p = 0; p < 2; p++) {
    #pragma unroll
    for (int mm = 0; mm < 2; mm++)
      #pragma unroll
      for (int nt = 0; nt < 9; nt++) {
        int col = nt * 16 + fr;
        int cl = col - 72 * p;
        if (cl >= 0 && cl < 72) {
          #pragma unroll
          for (int rg = 0; rg < 4; rg++) {
            int row = w * 32 + mm * 16 + quad * 4 + rg;
            ep[row * 73 + cl] = acc[mm][nt][rg];
          }
        }
      }
    __syncthreads();
    {
      int dloc = t >> 1, bloc = t & 1;
      int bg = b0 + p * 2 + bloc;
      const float* yr = ep + dloc * 73 + bloc * 36;
      float m = yr[0];
      for (int r = 1; r < R_; r++) m = fmaxf(m, yr[r]);
      float s = 0.f, wsum = 0.f;
      for (int r = 0; r < R_; r++) {
        float yv = yr[r];
        float e = __expf(yv - m);
        s += e; wsum += e * yv;
      }
      // bconv[d] is constant over r: softmax mask unchanged, add after weighted sum
      float img = wsum / s + bconv[dt0 + dloc];
      imgvec[((size_t)qg * B_ + bg) * D_ + dt0 + dloc] = img;
    }
    __syncthreads();
  }
}

// ---------------- k_sims: l2norm + dot -> out[b][q] ----------------
__global__ __launch_bounds__(256) void k_sims(const float* __restrict__ imgvec,
    const float* __restrict__ capvec, float* __restrict__ out)
{
  const int q = blockIdx.x, b = blockIdx.y, t = threadIdx.x;
  const float4* iv = (const float4*)(imgvec + ((size_t)q * B_ + b) * D_);
  const float4* cv = (const float4*)(capvec + (size_t)q * D_);
  float4 a = iv[t], c = cv[t];
  float ss = a.x*a.x + a.y*a.y + a.z*a.z + a.w*a.w;
  float dt = a.x*c.x + a.y*c.y + a.z*c.z + a.w*c.w;
  #pragma unroll
  for (int off = 32; off > 0; off >>= 1) {
    ss += __shfl_down(ss, off);
    dt += __shfl_down(dt, off);
  }
  __shared__ float r1[4], r2[4];
  if ((t & 63) == 0) { r1[t >> 6] = ss; r2[t >> 6] = dt; }
  __syncthreads();
  if (t == 0) {
    ss = r1[0] + r1[1] + r1[2] + r1[3];
    dt = r2[0] + r2[1] + r2[2] + r2[3];
    out[(size_t)b * Q_ + q] = dt * rsqrtf(ss);
  }
}

extern "C" void kernel_launch(void* const* d_in, const int* in_sizes, int n_in,
                              void* d_out, int out_size, void* d_ws, size_t ws_size,
                              hipStream_t stream)
{
  (void)in_sizes; (void)n_in; (void)out_size;
  const float* img   = (const float*)d_in[0];
  const float* cap   = (const float*)d_in[1];
  // d_in[2] = lens : unused by the reference
  const float* Wred  = (const float*)d_in[3];
  const float* bred  = (const float*)d_in[4];
  const float* Wproj = (const float*)d_in[5];
  const float* bproj = (const float*)d_in[6];
  const float* Wconv = (const float*)d_in[7];
  const float* bconv = (const float*)d_in[8];
  float* out = (float*)d_out;

  char* ws = (char*)d_ws;
  const size_t XPB_B  = (size_t)B_ * RP_ * D_ * 2;       // 3,735,552
  const size_t WCBF_B = (size_t)D_ * D_ * 2;             // 2,097,152
  const size_t WPL_B  = (size_t)Q_ * 3 * D_ * 4;         //   589,824
  const size_t CAPV_B = (size_t)Q_ * D_ * 4;             //   196,608
  const size_t IMGV_B = (size_t)Q_ * B_ * D_ * 4;        // 9,437,184
  unsigned short* xpb  = (unsigned short*)ws;
  unsigned short* wcbf = (unsigned short*)(ws + XPB_B);
  float* wpl    = (float*)(ws + XPB_B + WCBF_B);
  float* capvec = (float*)(ws + XPB_B + WCBF_B + WPL_B);
  float* imgvec = (float*)(ws + XPB_B + WCBF_B + WPL_B + CAPV_B);
  const size_t FIXED = XPB_B + WCBF_B + WPL_B + CAPV_B + IMGV_B;  // 16,056,320
  unsigned short* cdbuf = (unsigned short*)(ws + FIXED);
  const size_t PERQ = (size_t)NPQ_ * D_ * 2;             // 3,538,944 per q

  int qchunk = 1;
  if (ws_size > FIXED + PERQ) {
    size_t c = (ws_size - FIXED) / PERQ;
    qchunk = (c > (size_t)Q_) ? Q_ : (int)c;
  }

  k_prep<<<dim3(Q_), dim3(256), 0, stream>>>(cap, Wred, bred, Wproj, bproj, wpl, capvec);
  k_xpad<<<dim3(B_ * RP_), dim3(256), 0, stream>>>(img, xpb);
  k_wcbf<<<dim3(512), dim3(256), 0, stream>>>(Wconv, wcbf);
  for (int q0 = 0; q0 < Q_; q0 += qchunk) {
    int qs = (Q_ - q0 < qchunk) ? (Q_ - q0) : qchunk;
    k_cd<<<dim3(B_ / 2, qs), dim3(256), 0, stream>>>(xpb, wpl, cdbuf, q0);
    k_gemm<<<dim3(NPQ_ / BN_, D_ / BM_, qs), dim3(256), 0, stream>>>(wcbf, cdbuf, bconv, imgvec, q0);
  }
  k_sims<<<dim3(Q_, B_), dim3(256), 0, stream>>>(imgvec, capvec, out);
}

// Round 3
// 323.842 us; speedup vs baseline: 2.3173x; 2.3173x over previous
//
#include <hip/hip_runtime.h>

#define D_   1024
#define B_   48
#define Q_   48
#define R_   36
#define RP_  38
#define DQ_  256
#define NPQ_ 1728   // B_*R_

typedef __attribute__((ext_vector_type(8))) short bf16x8;
typedef __attribute__((ext_vector_type(8))) unsigned short u16x8;
typedef __attribute__((ext_vector_type(4))) float f32x4;

static __device__ __forceinline__ unsigned short f2bf(float f) {
  union { float f; unsigned u; } v; v.f = f;
  unsigned r = v.u + 0x7fffu + ((v.u >> 16) & 1u);   // round-to-nearest-even
  return (unsigned short)(r >> 16);
}
static __device__ __forceinline__ float bf2f(unsigned short h) {
  union { unsigned u; float f; } v; v.u = ((unsigned)h) << 16; return v.f;
}
static __device__ __forceinline__ void gload_lds16(const void* g, void* s) {
  __builtin_amdgcn_global_load_lds(
      (const __attribute__((address_space(1))) unsigned int*)g,
      (__attribute__((address_space(3))) unsigned int*)s, 16, 0, 0);
}

// ---------------- k_capv: cap_vec = l2norm(cap0) ----------------
__global__ __launch_bounds__(256) void k_capv(const float* __restrict__ cap_embed,
                                              float* __restrict__ capvec)
{
  const int q = blockIdx.x, t = threadIdx.x;
  const int w = t >> 6, lane = t & 63;
  __shared__ float red[4];
  float4 v = ((const float4*)(cap_embed + (size_t)q * 32 * D_))[t];  // token 0
  float ss = v.x*v.x + v.y*v.y + v.z*v.z + v.w*v.w;
  #pragma unroll
  for (int off = 32; off > 0; off >>= 1) ss += __shfl_down(ss, off);
  if (lane == 0) red[w] = ss;
  __syncthreads();
  float rinv = rsqrtf(red[0] + red[1] + red[2] + red[3]);
  float4 cv; cv.x = v.x*rinv; cv.y = v.y*rinv; cv.z = v.z*rinv; cv.w = v.w*rinv;
  ((float4*)(capvec + (size_t)q * D_))[t] = cv;
}

// ---------------- k_repr: cap_repr[q][o] = Wred[o,:].cap0[q] + bred[o] ----------------
// wave-per-output: grid (Q, 64), 4 waves/block
__global__ __launch_bounds__(256) void k_repr(const float* __restrict__ cap_embed,
    const float* __restrict__ Wred, const float* __restrict__ bred,
    float* __restrict__ repr)
{
  const int q = blockIdx.x;
  const int w = threadIdx.x >> 6, lane = threadIdx.x & 63;
  const int o = blockIdx.y * 4 + w;   // 0..255
  const float4* c4 = (const float4*)(cap_embed + (size_t)q * 32 * D_);
  const float4* wr = (const float4*)(Wred + (size_t)o * D_);
  float acc = 0.f;
  #pragma unroll
  for (int j = 0; j < 4; j++) {
    float4 a = wr[lane + j*64], c = c4[lane + j*64];
    acc += a.x*c.x + a.y*c.y + a.z*c.z + a.w*c.w;
  }
  #pragma unroll
  for (int off = 32; off > 0; off >>= 1) acc += __shfl_down(acc, off);
  if (lane == 0) repr[(size_t)q * DQ_ + o] = acc + bred[o];
}

// ---------------- k_wdyn: logits (3 per d) + K=3 softmax -> wpl planes [q][k][d] --------
// wave-per-d: grid (Q, 256), 4 waves/block
__global__ __launch_bounds__(256) void k_wdyn(const float* __restrict__ repr,
    const float* __restrict__ Wproj, const float* __restrict__ bproj,
    float* __restrict__ wpl)
{
  const int q = blockIdx.x;
  const int w = threadIdx.x >> 6, lane = threadIdx.x & 63;
  const int d = blockIdx.y * 4 + w;   // 0..1023
  float4 r4 = ((const float4*)(repr + (size_t)q * DQ_))[lane];
  float a0, a1, a2;
  {
    const float4* p0 = (const float4*)(Wproj + (size_t)(d*3 + 0) * DQ_);
    const float4* p1 = (const float4*)(Wproj + (size_t)(d*3 + 1) * DQ_);
    const float4* p2 = (const float4*)(Wproj + (size_t)(d*3 + 2) * DQ_);
    float4 v0 = p0[lane], v1 = p1[lane], v2 = p2[lane];
    a0 = v0.x*r4.x + v0.y*r4.y + v0.z*r4.z + v0.w*r4.w;
    a1 = v1.x*r4.x + v1.y*r4.y + v1.z*r4.z + v1.w*r4.w;
    a2 = v2.x*r4.x + v2.y*r4.y + v2.z*r4.z + v2.w*r4.w;
  }
  #pragma unroll
  for (int off = 32; off > 0; off >>= 1) {
    a0 += __shfl_down(a0, off);
    a1 += __shfl_down(a1, off);
    a2 += __shfl_down(a2, off);
  }
  if (lane == 0) {
    float l0 = a0 + bproj[d*3], l1 = a1 + bproj[d*3+1], l2 = a2 + bproj[d*3+2];
    float m = fmaxf(l0, fmaxf(l1, l2));
    float e0 = __expf(l0-m), e1 = __expf(l1-m), e2 = __expf(l2-m);
    float inv = 1.0f / (e0 + e1 + e2);
    wpl[((size_t)q*3 + 0) * D_ + d] = e0 * inv;
    wpl[((size_t)q*3 + 1) * D_ + d] = e1 * inv;
    wpl[((size_t)q*3 + 2) * D_ + d] = e2 * inv;
  }
}

// ---------------- k_xpad: img_embed -> bf16, layout [b][rp][c] (logical, no swizzle) ----
__global__ __launch_bounds__(256) void k_xpad(const float* __restrict__ img,
                                              unsigned short* __restrict__ xpb)
{
  const int br = blockIdx.x;            // 0..48*38-1
  const int b = br / RP_, rp = br % RP_;
  const int c = threadIdx.x * 4;
  short4 o;
  if (rp == 0 || rp == RP_ - 1) { o.x = 0; o.y = 0; o.z = 0; o.w = 0; }
  else {
    float4 v = *(const float4*)&img[((size_t)b * R_ + (rp-1)) * D_ + c];
    o.x = (short)f2bf(v.x); o.y = (short)f2bf(v.y);
    o.z = (short)f2bf(v.z); o.w = (short)f2bf(v.w);
  }
  *(short4*)&xpb[(size_t)br * D_ + c] = o;
}

// ---------------- k_wcbf: Wconv fp32 -> bf16, k-group XOR swizzle per row ----------------
// physical group g holds logical group g ^ ((row>>1)&3) within each 32-k tile
__global__ __launch_bounds__(256) void k_wcbf(const float* __restrict__ Wconv,
                                              unsigned short* __restrict__ wcbf)
{
  const int tid = blockIdx.x * 256 + threadIdx.x;   // 131072 threads
  const int m = tid >> 7;        // row 0..1023
  const int gg = tid & 127;      // group-of-8 within row
  const int tile = gg >> 2, g = gg & 3;
  const int gl = g ^ ((m >> 1) & 3);                // logical group stored at slot g
  const float* src = Wconv + (size_t)m * D_ + tile * 32 + gl * 8;
  float4 v0 = *(const float4*)src, v1 = *(const float4*)(src + 4);
  u16x8 o;
  o[0] = f2bf(v0.x); o[1] = f2bf(v0.y); o[2] = f2bf(v0.z); o[3] = f2bf(v0.w);
  o[4] = f2bf(v1.x); o[5] = f2bf(v1.y); o[6] = f2bf(v1.z); o[7] = f2bf(v1.w);
  *(u16x8*)&wcbf[(size_t)m * D_ + tile * 32 + g * 8] = o;
}

// ---------------- k_cd: conv_dyn bf16 [ql][n=b*36+r][c], swizzled k-groups --------------
__global__ __launch_bounds__(256) void k_cd(const unsigned short* __restrict__ xpb,
    const float* __restrict__ wpl, unsigned short* __restrict__ cd, int qstart)
{
  const int ql = blockIdx.y, qg = qstart + ql;
  const int t = threadIdx.x;
  const int bloc = t >> 7;                  // 0..1
  const int b = blockIdx.x * 2 + bloc;
  const int gg = t & 127;                   // group-of-8 channels
  const int tile = gg >> 2, g = gg & 3;
  const int ch = gg * 8;

  float w0[8], w1[8], w2[8];
  {
    const float4* p0 = (const float4*)(wpl + ((size_t)qg*3 + 0)*D_ + ch);
    const float4* p1 = (const float4*)(wpl + ((size_t)qg*3 + 1)*D_ + ch);
    const float4* p2 = (const float4*)(wpl + ((size_t)qg*3 + 2)*D_ + ch);
    float4 a0 = p0[0], a1 = p0[1], b0 = p1[0], b1 = p1[1], d0 = p2[0], d1 = p2[1];
    w0[0]=a0.x; w0[1]=a0.y; w0[2]=a0.z; w0[3]=a0.w; w0[4]=a1.x; w0[5]=a1.y; w0[6]=a1.z; w0[7]=a1.w;
    w1[0]=b0.x; w1[1]=b0.y; w1[2]=b0.z; w1[3]=b0.w; w1[4]=b1.x; w1[5]=b1.y; w1[6]=b1.z; w1[7]=b1.w;
    w2[0]=d0.x; w2[1]=d0.y; w2[2]=d0.z; w2[3]=d0.w; w2[4]=d1.x; w2[5]=d1.y; w2[6]=d1.z; w2[7]=d1.w;
  }
  const unsigned short* xb = xpb + (size_t)b * RP_ * D_ + ch;
  u16x8 ra = *(const u16x8*)&xb[0];
  u16x8 rb = *(const u16x8*)&xb[D_];
  unsigned short* outb = cd + ((size_t)ql * NPQ_ + (size_t)b * R_) * D_ + tile * 32;
  for (int r = 0; r < R_; r++) {
    u16x8 rc = *(const u16x8*)&xb[(size_t)(r + 2) * D_];
    u16x8 o;
    #pragma unroll
    for (int i = 0; i < 8; i++) {
      float y = w0[i]*bf2f(ra[i]) + w1[i]*bf2f(rb[i]) + w2[i]*bf2f(rc[i]);
      o[i] = f2bf(y);
    }
    int gp = g ^ (((b * 36 + r) >> 1) & 3);
    *(u16x8*)&outb[(size_t)r * D_ + gp * 8] = o;
    ra = rb; rb = rc;
  }
}

// ---------------- k_gemm: Y = Wconv @ Cd_q, fused r-softmax epilogue -> imgvec ----------
#define BM_ 128
#define BN_ 144
#define BK_ 64

__global__ __launch_bounds__(256, 2) void k_gemm(
    const unsigned short* __restrict__ wcbf, const unsigned short* __restrict__ cd,
    const float* __restrict__ bconv, float* __restrict__ imgvec, int qstart)
{
  __shared__ __align__(16) unsigned char smem[37376];   // max(A 16KB + B 18KB, ep 128*73*4)
  unsigned short* As = (unsigned short*)smem;            // 16 chunks x 512 bf16
  unsigned short* Bs = (unsigned short*)(smem + 16384);  // 18 chunks x 512 bf16
  float* ep = (float*)smem;                              // [128][73] fp32 (epilogue)

  const int t = threadIdx.x;
  const int w = t >> 6, lane = t & 63;
  const int nt0 = blockIdx.x * BN_;
  const int dt0 = blockIdx.y * BM_;
  const int ql = blockIdx.z, qg = qstart + ql;

  f32x4 acc[2][9];
  #pragma unroll
  for (int mm = 0; mm < 2; mm++)
    #pragma unroll
    for (int nt = 0; nt < 9; nt++)
      acc[mm][nt] = (f32x4){0.f, 0.f, 0.f, 0.f};

  const int lrow = lane >> 2;          // 0..15 (row within 16-row chunk)
  const int lc8  = (lane & 3) * 8;     // 0,8,16,24 (phys k offset within 32-tile)
  const unsigned short* Ag = wcbf + (size_t)dt0 * D_ + lc8;
  const unsigned short* Bg = cd + ((size_t)ql * NPQ_ + nt0) * D_ + lc8;
  const int fr = lane & 15;
  // swizzled fragment offset within a 16x32 chunk (shorts):
  const int fro = fr * 32 + ((((lane >> 4) ^ ((fr >> 1) & 3))) << 3);

  for (int k0 = 0; k0 < D_; k0 += BK_) {
    #pragma unroll
    for (int jj = 0; jj < 2; jj++) {             // A: 8 row-chunks x 2 k-halves
      int j = w + jj * 4;
      #pragma unroll
      for (int h = 0; h < 2; h++)
        gload_lds16(Ag + (size_t)(j*16 + lrow) * D_ + k0 + h*32,
                    As + (j*2 + h) * 512);
    }
    for (int u = w; u < 18; u += 4) {            // B: 9 row-chunks x 2 k-halves
      int jb = u >> 1, h = u & 1;
      gload_lds16(Bg + (size_t)(jb*16 + lrow) * D_ + k0 + h*32,
                  Bs + u * 512);
    }
    __syncthreads();
    #pragma unroll
    for (int s = 0; s < 2; s++) {
      bf16x8 aF[2], bF[9];
      #pragma unroll
      for (int mm = 0; mm < 2; mm++)
        aF[mm] = *(const bf16x8*)&As[(w*4 + mm*2 + s) * 512 + fro];
      #pragma unroll
      for (int nt = 0; nt < 9; nt++)
        bF[nt] = *(const bf16x8*)&Bs[(nt*2 + s) * 512 + fro];
      #pragma unroll
      for (int mm = 0; mm < 2; mm++)
        #pragma unroll
        for (int nt = 0; nt < 9; nt++)
          acc[mm][nt] = __builtin_amdgcn_mfma_f32_16x16x32_bf16(aF[mm], bF[nt], acc[mm][nt], 0, 0, 0);
    }
    __syncthreads();
  }

  // Epilogue: softmax over r (36 cols per b), two 72-col passes, ep pitch 73.
  const int quad = lane >> 4;
  const int b0 = nt0 / R_;   // first image-batch index of this tile (4 b's per tile)
  #pragma unroll
  for (int p = 0; p < 2; p++) {
    #pragma unroll
    for (int mm = 0; mm < 2; mm++)
      #pragma unroll
      for (int nt = 0; nt < 9; nt++) {
        int col = nt * 16 + fr;
        int cl = col - 72 * p;
        if (cl >= 0 && cl < 72) {
          #pragma unroll
          for (int rg = 0; rg < 4; rg++) {
            int row = w * 32 + mm * 16 + quad * 4 + rg;
            ep[row * 73 + cl] = acc[mm][nt][rg];
          }
        }
      }
    __syncthreads();
    {
      int dloc = t >> 1, bloc = t & 1;
      int bg = b0 + p * 2 + bloc;
      const float* yr = ep + dloc * 73 + bloc * 36;
      float m = yr[0];
      for (int r = 1; r < R_; r++) m = fmaxf(m, yr[r]);
      float s = 0.f, wsum = 0.f;
      for (int r = 0; r < R_; r++) {
        float yv = yr[r];
        float e = __expf(yv - m);
        s += e; wsum += e * yv;
      }
      // bconv[d] is constant over r: softmax mask unchanged, add after weighted sum
      float img = wsum / s + bconv[dt0 + dloc];
      imgvec[((size_t)qg * B_ + bg) * D_ + dt0 + dloc] = img;
    }
    __syncthreads();
  }
}

// ---------------- k_sims: l2norm + dot -> out[b][q] ----------------
__global__ __launch_bounds__(256) void k_sims(const float* __restrict__ imgvec,
    const float* __restrict__ capvec, float* __restrict__ out)
{
  const int q = blockIdx.x, b = blockIdx.y, t = threadIdx.x;
  const float4* iv = (const float4*)(imgvec + ((size_t)q * B_ + b) * D_);
  const float4* cv = (const float4*)(capvec + (size_t)q * D_);
  float4 a = iv[t], c = cv[t];
  float ss = a.x*a.x + a.y*a.y + a.z*a.z + a.w*a.w;
  float dt = a.x*c.x + a.y*c.y + a.z*c.z + a.w*c.w;
  #pragma unroll
  for (int off = 32; off > 0; off >>= 1) {
    ss += __shfl_down(ss, off);
    dt += __shfl_down(dt, off);
  }
  __shared__ float r1[4], r2[4];
  if ((t & 63) == 0) { r1[t >> 6] = ss; r2[t >> 6] = dt; }
  __syncthreads();
  if (t == 0) {
    ss = r1[0] + r1[1] + r1[2] + r1[3];
    dt = r2[0] + r2[1] + r2[2] + r2[3];
    out[(size_t)b * Q_ + q] = dt * rsqrtf(ss);
  }
}

extern "C" void kernel_launch(void* const* d_in, const int* in_sizes, int n_in,
                              void* d_out, int out_size, void* d_ws, size_t ws_size,
                              hipStream_t stream)
{
  (void)in_sizes; (void)n_in; (void)out_size;
  const float* img   = (const float*)d_in[0];
  const float* cap   = (const float*)d_in[1];
  // d_in[2] = lens : unused by the reference
  const float* Wred  = (const float*)d_in[3];
  const float* bred  = (const float*)d_in[4];
  const float* Wproj = (const float*)d_in[5];
  const float* bproj = (const float*)d_in[6];
  const float* Wconv = (const float*)d_in[7];
  const float* bconv = (const float*)d_in[8];
  float* out = (float*)d_out;

  char* ws = (char*)d_ws;
  const size_t XPB_B  = (size_t)B_ * RP_ * D_ * 2;       // 3,735,552
  const size_t WCBF_B = (size_t)D_ * D_ * 2;             // 2,097,152
  const size_t WPL_B  = (size_t)Q_ * 3 * D_ * 4;         //   589,824
  const size_t CAPV_B = (size_t)Q_ * D_ * 4;             //   196,608
  const size_t REPR_B = (size_t)Q_ * DQ_ * 4;            //    49,152
  const size_t IMGV_B = (size_t)Q_ * B_ * D_ * 4;        // 9,437,184
  unsigned short* xpb  = (unsigned short*)ws;
  unsigned short* wcbf = (unsigned short*)(ws + XPB_B);
  float* wpl    = (float*)(ws + XPB_B + WCBF_B);
  float* capvec = (float*)(ws + XPB_B + WCBF_B + WPL_B);
  float* repr   = (float*)(ws + XPB_B + WCBF_B + WPL_B + CAPV_B);
  float* imgvec = (float*)(ws + XPB_B + WCBF_B + WPL_B + CAPV_B + REPR_B);
  const size_t FIXED = XPB_B + WCBF_B + WPL_B + CAPV_B + REPR_B + IMGV_B;
  unsigned short* cdbuf = (unsigned short*)(ws + FIXED);
  const size_t PERQ = (size_t)NPQ_ * D_ * 2;             // 3,538,944 per q

  int qchunk = 1;
  if (ws_size > FIXED + PERQ) {
    size_t c = (ws_size - FIXED) / PERQ;
    qchunk = (c > (size_t)Q_) ? Q_ : (int)c;
  }

  k_capv<<<dim3(Q_), dim3(256), 0, stream>>>(cap, capvec);
  k_repr<<<dim3(Q_, 64), dim3(256), 0, stream>>>(cap, Wred, bred, repr);
  k_wdyn<<<dim3(Q_, 256), dim3(256), 0, stream>>>(repr, Wproj, bproj, wpl);
  k_xpad<<<dim3(B_ * RP_), dim3(256), 0, stream>>>(img, xpb);
  k_wcbf<<<dim3(512), dim3(256), 0, stream>>>(Wconv, wcbf);
  for (int q0 = 0; q0 < Q_; q0 += qchunk) {
    int qs = (Q_ - q0 < qchunk) ? (Q_ - q0) : qchunk;
    k_cd<<<dim3(B_ / 2, qs), dim3(256), 0, stream>>>(xpb, wpl, cdbuf, q0);
    k_gemm<<<dim3(NPQ_ / BN_, D_ / BM_, qs), dim3(256), 0, stream>>>(wcbf, cdbuf, bconv, imgvec, q0);
  }
  k_sims<<<dim3(Q_, B_), dim3(256), 0, stream>>>(imgvec, capvec, out);
}

// Round 4
// 289.048 us; speedup vs baseline: 2.5962x; 1.1204x over previous
//
#include <hip/hip_runtime.h>

#define D_   1024
#define B_   48
#define Q_   48
#define R_   36
#define RP_  38
#define DQ_  256
#define NPQ_ 1728   // B_*R_

typedef __attribute__((ext_vector_type(8))) short bf16x8;
typedef __attribute__((ext_vector_type(8))) unsigned short u16x8;
typedef __attribute__((ext_vector_type(4))) float f32x4;

static __device__ __forceinline__ unsigned short f2bf(float f) {
  union { float f; unsigned u; } v; v.f = f;
  unsigned r = v.u + 0x7fffu + ((v.u >> 16) & 1u);   // round-to-nearest-even
  return (unsigned short)(r >> 16);
}
static __device__ __forceinline__ float bf2f(unsigned short h) {
  union { unsigned u; float f; } v; v.u = ((unsigned)h) << 16; return v.f;
}
static __device__ __forceinline__ void gload_lds16(const void* g, void* s) {
  __builtin_amdgcn_global_load_lds(
      (const __attribute__((address_space(1))) unsigned int*)g,
      (__attribute__((address_space(3))) unsigned int*)s, 16, 0, 0);
}

// ---------------- k_repr: cap_repr[q][o] = Wred[o,:].cap0[q] + bred[o] ----------------
// wave-per-output: grid (Q, 64), 4 waves/block
__global__ __launch_bounds__(256) void k_repr(const float* __restrict__ cap_embed,
    const float* __restrict__ Wred, const float* __restrict__ bred,
    float* __restrict__ repr)
{
  const int q = blockIdx.x;
  const int w = threadIdx.x >> 6, lane = threadIdx.x & 63;
  const int o = blockIdx.y * 4 + w;   // 0..255
  const float4* c4 = (const float4*)(cap_embed + (size_t)q * 32 * D_);
  const float4* wr = (const float4*)(Wred + (size_t)o * D_);
  float acc = 0.f;
  #pragma unroll
  for (int j = 0; j < 4; j++) {
    float4 a = wr[lane + j*64], c = c4[lane + j*64];
    acc += a.x*c.x + a.y*c.y + a.z*c.z + a.w*c.w;
  }
  #pragma unroll
  for (int off = 32; off > 0; off >>= 1) acc += __shfl_down(acc, off);
  if (lane == 0) repr[(size_t)q * DQ_ + o] = acc + bred[o];
}

// ---------------- k_wdyn: logits (3 per d) + K=3 softmax -> wpl planes [q][k][d] --------
// wave-per-d: grid (Q, 256), 4 waves/block
__global__ __launch_bounds__(256) void k_wdyn(const float* __restrict__ repr,
    const float* __restrict__ Wproj, const float* __restrict__ bproj,
    float* __restrict__ wpl)
{
  const int q = blockIdx.x;
  const int w = threadIdx.x >> 6, lane = threadIdx.x & 63;
  const int d = blockIdx.y * 4 + w;   // 0..1023
  float4 r4 = ((const float4*)(repr + (size_t)q * DQ_))[lane];
  float a0, a1, a2;
  {
    const float4* p0 = (const float4*)(Wproj + (size_t)(d*3 + 0) * DQ_);
    const float4* p1 = (const float4*)(Wproj + (size_t)(d*3 + 1) * DQ_);
    const float4* p2 = (const float4*)(Wproj + (size_t)(d*3 + 2) * DQ_);
    float4 v0 = p0[lane], v1 = p1[lane], v2 = p2[lane];
    a0 = v0.x*r4.x + v0.y*r4.y + v0.z*r4.z + v0.w*r4.w;
    a1 = v1.x*r4.x + v1.y*r4.y + v1.z*r4.z + v1.w*r4.w;
    a2 = v2.x*r4.x + v2.y*r4.y + v2.z*r4.z + v2.w*r4.w;
  }
  #pragma unroll
  for (int off = 32; off > 0; off >>= 1) {
    a0 += __shfl_down(a0, off);
    a1 += __shfl_down(a1, off);
    a2 += __shfl_down(a2, off);
  }
  if (lane == 0) {
    float l0 = a0 + bproj[d*3], l1 = a1 + bproj[d*3+1], l2 = a2 + bproj[d*3+2];
    float m = fmaxf(l0, fmaxf(l1, l2));
    float e0 = __expf(l0-m), e1 = __expf(l1-m), e2 = __expf(l2-m);
    float inv = 1.0f / (e0 + e1 + e2);
    wpl[((size_t)q*3 + 0) * D_ + d] = e0 * inv;
    wpl[((size_t)q*3 + 1) * D_ + d] = e1 * inv;
    wpl[((size_t)q*3 + 2) * D_ + d] = e2 * inv;
  }
}

// ---------------- k_xpad: img_embed -> bf16, layout [b][rp][c] ----------------
__global__ __launch_bounds__(256) void k_xpad(const float* __restrict__ img,
                                              unsigned short* __restrict__ xpb)
{
  const int br = blockIdx.x;            // 0..48*38-1
  const int b = br / RP_, rp = br % RP_;
  const int c = threadIdx.x * 4;
  short4 o;
  if (rp == 0 || rp == RP_ - 1) { o.x = 0; o.y = 0; o.z = 0; o.w = 0; }
  else {
    float4 v = *(const float4*)&img[((size_t)b * R_ + (rp-1)) * D_ + c];
    o.x = (short)f2bf(v.x); o.y = (short)f2bf(v.y);
    o.z = (short)f2bf(v.z); o.w = (short)f2bf(v.w);
  }
  *(short4*)&xpb[(size_t)br * D_ + c] = o;
}

// ---------------- k_wcbf: Wconv fp32 -> bf16, k-group XOR swizzle per row ----------------
// physical group g holds logical group g ^ ((row>>1)&3) within each 32-k tile
__global__ __launch_bounds__(256) void k_wcbf(const float* __restrict__ Wconv,
                                              unsigned short* __restrict__ wcbf)
{
  const int tid = blockIdx.x * 256 + threadIdx.x;   // 131072 threads
  const int m = tid >> 7;        // row 0..1023
  const int gg = tid & 127;      // group-of-8 within row
  const int tile = gg >> 2, g = gg & 3;
  const int gl = g ^ ((m >> 1) & 3);                // logical group stored at slot g
  const float* src = Wconv + (size_t)m * D_ + tile * 32 + gl * 8;
  float4 v0 = *(const float4*)src, v1 = *(const float4*)(src + 4);
  u16x8 o;
  o[0] = f2bf(v0.x); o[1] = f2bf(v0.y); o[2] = f2bf(v0.z); o[3] = f2bf(v0.w);
  o[4] = f2bf(v1.x); o[5] = f2bf(v1.y); o[6] = f2bf(v1.z); o[7] = f2bf(v1.w);
  *(u16x8*)&wcbf[(size_t)m * D_ + tile * 32 + g * 8] = o;
}

// ---------------- k_cd: conv_dyn bf16 [ql][n=b*36+r][c], swizzled k-groups --------------
__global__ __launch_bounds__(256) void k_cd(const unsigned short* __restrict__ xpb,
    const float* __restrict__ wpl, unsigned short* __restrict__ cd, int qstart)
{
  const int ql = blockIdx.y, qg = qstart + ql;
  const int t = threadIdx.x;
  const int bloc = t >> 7;                  // 0..1
  const int b = blockIdx.x * 2 + bloc;
  const int gg = t & 127;                   // group-of-8 channels
  const int tile = gg >> 2, g = gg & 3;
  const int ch = gg * 8;

  float w0[8], w1[8], w2[8];
  {
    const float4* p0 = (const float4*)(wpl + ((size_t)qg*3 + 0)*D_ + ch);
    const float4* p1 = (const float4*)(wpl + ((size_t)qg*3 + 1)*D_ + ch);
    const float4* p2 = (const float4*)(wpl + ((size_t)qg*3 + 2)*D_ + ch);
    float4 a0 = p0[0], a1 = p0[1], b0 = p1[0], b1 = p1[1], d0 = p2[0], d1 = p2[1];
    w0[0]=a0.x; w0[1]=a0.y; w0[2]=a0.z; w0[3]=a0.w; w0[4]=a1.x; w0[5]=a1.y; w0[6]=a1.z; w0[7]=a1.w;
    w1[0]=b0.x; w1[1]=b0.y; w1[2]=b0.z; w1[3]=b0.w; w1[4]=b1.x; w1[5]=b1.y; w1[6]=b1.z; w1[7]=b1.w;
    w2[0]=d0.x; w2[1]=d0.y; w2[2]=d0.z; w2[3]=d0.w; w2[4]=d1.x; w2[5]=d1.y; w2[6]=d1.z; w2[7]=d1.w;
  }
  const unsigned short* xb = xpb + (size_t)b * RP_ * D_ + ch;
  u16x8 ra = *(const u16x8*)&xb[0];
  u16x8 rb = *(const u16x8*)&xb[D_];
  unsigned short* outb = cd + ((size_t)ql * NPQ_ + (size_t)b * R_) * D_ + tile * 32;
  for (int r = 0; r < R_; r++) {
    u16x8 rc = *(const u16x8*)&xb[(size_t)(r + 2) * D_];
    u16x8 o;
    #pragma unroll
    for (int i = 0; i < 8; i++) {
      float y = w0[i]*bf2f(ra[i]) + w1[i]*bf2f(rb[i]) + w2[i]*bf2f(rc[i]);
      o[i] = f2bf(y);
    }
    int gp = g ^ (((b * 36 + r) >> 1) & 3);
    *(u16x8*)&outb[(size_t)r * D_ + gp * 8] = o;
    ra = rb; rb = rc;
  }
}

// ---------------- k_gemm: Y = Wconv @ Cd_q, fused r-softmax epilogue -> imgvec ----------
// BM=256: 4 m-tiles/wave -> frag ds_reads per MFMA drop 0.61 -> 0.36 (LDS-read-bound fix)
#define BM_ 256
#define BN_ 144
#define BK_ 64

__global__ __launch_bounds__(256, 2) void k_gemm(
    const unsigned short* __restrict__ wcbf, const unsigned short* __restrict__ cd,
    const float* __restrict__ bconv, float* __restrict__ imgvec, int qstart)
{
  __shared__ __align__(16) unsigned char smem[51200];   // A 32KB + B 18KB; ep 37.4KB reuses front
  unsigned short* As = (unsigned short*)smem;            // 32 quanta x 512 bf16 (chunk-major)
  unsigned short* Bs = (unsigned short*)(smem + 32768);  // 18 quanta x 512 bf16
  float* ep = (float*)smem;                              // [128][73] fp32 (epilogue)

  const int t = threadIdx.x;
  const int w = t >> 6, lane = t & 63;
  const int nt0 = blockIdx.x * BN_;
  const int dt0 = blockIdx.y * BM_;
  const int ql = blockIdx.z, qg = qstart + ql;

  f32x4 acc[4][9];
  #pragma unroll
  for (int mm = 0; mm < 4; mm++)
    #pragma unroll
    for (int nt = 0; nt < 9; nt++)
      acc[mm][nt] = (f32x4){0.f, 0.f, 0.f, 0.f};

  const int lrow = lane >> 2;          // 0..15 (row within 16-row chunk)
  const int lc8  = (lane & 3) * 8;     // 0,8,16,24 (phys k offset within 32-tile)
  const unsigned short* Ag = wcbf + (size_t)dt0 * D_ + lc8;
  const unsigned short* Bg = cd + ((size_t)ql * NPQ_ + nt0) * D_ + lc8;
  const int fr = lane & 15;
  // swizzled fragment offset within a 16x32 chunk (shorts):
  const int fro = fr * 32 + ((((lane >> 4) ^ ((fr >> 1) & 3))) << 3);

  for (int k0 = 0; k0 < D_; k0 += BK_) {
    #pragma unroll
    for (int jj = 0; jj < 8; jj++) {             // A: 16 row-chunks x 2 k-halves = 32 quanta
      int u = w + jj * 4;                        // u = ja*2 + h
      int ja = u >> 1, h = u & 1;
      gload_lds16(Ag + (size_t)(ja*16 + lrow) * D_ + k0 + h*32, As + u * 512);
    }
    for (int u = w; u < 18; u += 4) {            // B: 9 row-chunks x 2 k-halves
      int jb = u >> 1, h = u & 1;
      gload_lds16(Bg + (size_t)(jb*16 + lrow) * D_ + k0 + h*32, Bs + u * 512);
    }
    __syncthreads();
    #pragma unroll
    for (int s = 0; s < 2; s++) {
      bf16x8 aF[4], bF[9];
      #pragma unroll
      for (int mm = 0; mm < 4; mm++)
        aF[mm] = *(const bf16x8*)&As[((w*4 + mm)*2 + s) * 512 + fro];
      #pragma unroll
      for (int nt = 0; nt < 9; nt++)
        bF[nt] = *(const bf16x8*)&Bs[(nt*2 + s) * 512 + fro];
      #pragma unroll
      for (int mm = 0; mm < 4; mm++)
        #pragma unroll
        for (int nt = 0; nt < 9; nt++)
          acc[mm][nt] = __builtin_amdgcn_mfma_f32_16x16x32_bf16(aF[mm], bF[nt], acc[mm][nt], 0, 0, 0);
    }
    __syncthreads();
  }

  // Epilogue: softmax over r (36 cols per b). 2 row-halves (pp) x 2 col-halves (p),
  // ep[128][73] fp32. Wave w owns rows w*64..w*64+63 -> half pp = w>>1.
  const int quad = lane >> 4;
  const int b0 = nt0 / R_;   // first image-batch index of this tile (4 b's per tile)
  #pragma unroll
  for (int pp = 0; pp < 2; pp++) {
    #pragma unroll
    for (int p = 0; p < 2; p++) {
      if ((w >> 1) == pp) {
        #pragma unroll
        for (int mm = 0; mm < 4; mm++)
          #pragma unroll
          for (int nt = 0; nt < 9; nt++) {
            int col = nt * 16 + fr;
            int cl = col - 72 * p;
            if (cl >= 0 && cl < 72) {
              #pragma unroll
              for (int rg = 0; rg < 4; rg++) {
                int rloc = (w & 1) * 64 + mm * 16 + quad * 4 + rg;  // 0..127
                ep[rloc * 73 + cl] = acc[mm][nt][rg];
              }
            }
          }
      }
      __syncthreads();
      {
        int dloc = t >> 1, bloc = t & 1;
        int bg = b0 + p * 2 + bloc;
        int dg = dt0 + pp * 128 + dloc;
        const float* yr = ep + dloc * 73 + bloc * 36;
        float m = yr[0];
        for (int r = 1; r < R_; r++) m = fmaxf(m, yr[r]);
        float s = 0.f, wsum = 0.f;
        for (int r = 0; r < R_; r++) {
          float yv = yr[r];
          float e = __expf(yv - m);
          s += e; wsum += e * yv;
        }
        // bconv[d] constant over r: softmax mask unchanged, add after weighted sum
        float img = wsum / s + bconv[dg];
        imgvec[((size_t)qg * B_ + bg) * D_ + dg] = img;
      }
      __syncthreads();
    }
  }
}

// ---------------- k_sims: l2norm(img) . l2norm(cap0) -> out[b][q] ----------------
__global__ __launch_bounds__(256) void k_sims(const float* __restrict__ imgvec,
    const float* __restrict__ cap_embed, float* __restrict__ out)
{
  const int q = blockIdx.x, b = blockIdx.y, t = threadIdx.x;
  const float4* iv = (const float4*)(imgvec + ((size_t)q * B_ + b) * D_);
  const float4* cv = (const float4*)(cap_embed + (size_t)q * 32 * D_);  // token 0
  float4 a = iv[t], c = cv[t];
  float ss = a.x*a.x + a.y*a.y + a.z*a.z + a.w*a.w;
  float sc = c.x*c.x + c.y*c.y + c.z*c.z + c.w*c.w;
  float dt = a.x*c.x + a.y*c.y + a.z*c.z + a.w*c.w;
  #pragma unroll
  for (int off = 32; off > 0; off >>= 1) {
    ss += __shfl_down(ss, off);
    sc += __shfl_down(sc, off);
    dt += __shfl_down(dt, off);
  }
  __shared__ float r1[4], r2[4], r3[4];
  if ((t & 63) == 0) { r1[t >> 6] = ss; r2[t >> 6] = sc; r3[t >> 6] = dt; }
  __syncthreads();
  if (t == 0) {
    ss = r1[0] + r1[1] + r1[2] + r1[3];
    sc = r2[0] + r2[1] + r2[2] + r2[3];
    dt = r3[0] + r3[1] + r3[2] + r3[3];
    out[(size_t)b * Q_ + q] = dt * rsqrtf(ss) * rsqrtf(sc);
  }
}

extern "C" void kernel_launch(void* const* d_in, const int* in_sizes, int n_in,
                              void* d_out, int out_size, void* d_ws, size_t ws_size,
                              hipStream_t stream)
{
  (void)in_sizes; (void)n_in; (void)out_size;
  const float* img   = (const float*)d_in[0];
  const float* cap   = (const float*)d_in[1];
  // d_in[2] = lens : unused by the reference
  const float* Wred  = (const float*)d_in[3];
  const float* bred  = (const float*)d_in[4];
  const float* Wproj = (const float*)d_in[5];
  const float* bproj = (const float*)d_in[6];
  const float* Wconv = (const float*)d_in[7];
  const float* bconv = (const float*)d_in[8];
  float* out = (float*)d_out;

  char* ws = (char*)d_ws;
  const size_t XPB_B  = (size_t)B_ * RP_ * D_ * 2;       // 3,735,552
  const size_t WCBF_B = (size_t)D_ * D_ * 2;             // 2,097,152
  const size_t WPL_B  = (size_t)Q_ * 3 * D_ * 4;         //   589,824
  const size_t REPR_B = (size_t)Q_ * DQ_ * 4;            //    49,152
  const size_t IMGV_B = (size_t)Q_ * B_ * D_ * 4;        // 9,437,184
  unsigned short* xpb  = (unsigned short*)ws;
  unsigned short* wcbf = (unsigned short*)(ws + XPB_B);
  float* wpl    = (float*)(ws + XPB_B + WCBF_B);
  float* repr   = (float*)(ws + XPB_B + WCBF_B + WPL_B);
  float* imgvec = (float*)(ws + XPB_B + WCBF_B + WPL_B + REPR_B);
  const size_t FIXED = XPB_B + WCBF_B + WPL_B + REPR_B + IMGV_B;
  unsigned short* cdbuf = (unsigned short*)(ws + FIXED);
  const size_t PERQ = (size_t)NPQ_ * D_ * 2;             // 3,538,944 per q

  int qchunk = 1;
  if (ws_size > FIXED + PERQ) {
    size_t c = (ws_size - FIXED) / PERQ;
    qchunk = (c > (size_t)Q_) ? Q_ : (int)c;
  }

  k_repr<<<dim3(Q_, 64), dim3(256), 0, stream>>>(cap, Wred, bred, repr);
  k_wdyn<<<dim3(Q_, 256), dim3(256), 0, stream>>>(repr, Wproj, bproj, wpl);
  k_xpad<<<dim3(B_ * RP_), dim3(256), 0, stream>>>(img, xpb);
  k_wcbf<<<dim3(512), dim3(256), 0, stream>>>(Wconv, wcbf);
  for (int q0 = 0; q0 < Q_; q0 += qchunk) {
    int qs = (Q_ - q0 < qchunk) ? (Q_ - q0) : qchunk;
    k_cd<<<dim3(B_ / 2, qs), dim3(256), 0, stream>>>(xpb, wpl, cdbuf, q0);
    k_gemm<<<dim3(NPQ_ / BN_, D_ / BM_, qs), dim3(256), 0, stream>>>(wcbf, cdbuf, bconv, imgvec, q0);
  }
  k_sims<<<dim3(Q_, B_), dim3(256), 0, stream>>>(imgvec, cap, out);
}

// Round 5
// 287.604 us; speedup vs baseline: 2.6092x; 1.0050x over previous
//
#include <hip/hip_runtime.h>

#define D_   1024
#define B_   48
#define Q_   48
#define R_   36
#define RP_  38
#define DQ_  256
#define NPQ_ 1728   // B_*R_

typedef __attribute__((ext_vector_type(8))) short bf16x8;
typedef __attribute__((ext_vector_type(8))) unsigned short u16x8;
typedef __attribute__((ext_vector_type(4))) float f32x4;

static __device__ __forceinline__ unsigned short f2bf(float f) {
  union { float f; unsigned u; } v; v.f = f;
  unsigned r = v.u + 0x7fffu + ((v.u >> 16) & 1u);   // round-to-nearest-even
  return (unsigned short)(r >> 16);
}
static __device__ __forceinline__ float bf2f(unsigned short h) {
  union { unsigned u; float f; } v; v.u = ((unsigned)h) << 16; return v.f;
}
static __device__ __forceinline__ void gload_lds16(const void* g, void* s) {
  __builtin_amdgcn_global_load_lds(
      (const __attribute__((address_space(1))) unsigned int*)g,
      (__attribute__((address_space(3))) unsigned int*)s, 16, 0, 0);
}

// ---------------- k_pre: fused xpad (1824 blocks) + wcbf (512) + repr (3072) ----------
__global__ __launch_bounds__(256) void k_pre(
    const float* __restrict__ img, unsigned short* __restrict__ xpb,
    const float* __restrict__ Wconv, unsigned short* __restrict__ wcbf,
    const float* __restrict__ cap_embed, const float* __restrict__ Wred,
    const float* __restrict__ bred, float* __restrict__ repr)
{
  const int bx = blockIdx.x, t = threadIdx.x;
  if (bx < B_ * RP_) {
    // --- xpad: img_embed -> bf16, layout [b][rp][c], rp zero-padded ---
    const int b = bx / RP_, rp = bx % RP_;
    const int c = t * 4;
    short4 o;
    if (rp == 0 || rp == RP_ - 1) { o.x = 0; o.y = 0; o.z = 0; o.w = 0; }
    else {
      float4 v = *(const float4*)&img[((size_t)b * R_ + (rp-1)) * D_ + c];
      o.x = (short)f2bf(v.x); o.y = (short)f2bf(v.y);
      o.z = (short)f2bf(v.z); o.w = (short)f2bf(v.w);
    }
    *(short4*)&xpb[(size_t)bx * D_ + c] = o;
  } else if (bx < B_ * RP_ + 512) {
    // --- wcbf: Wconv fp32 -> bf16 with k-group XOR swizzle per row ---
    const int tid = (bx - B_ * RP_) * 256 + t;        // 131072 threads
    const int m = tid >> 7;        // row 0..1023
    const int gg = tid & 127;      // group-of-8 within row
    const int tile = gg >> 2, g = gg & 3;
    const int gl = g ^ ((m >> 1) & 3);                // logical group stored at slot g
    const float* src = Wconv + (size_t)m * D_ + tile * 32 + gl * 8;
    float4 v0 = *(const float4*)src, v1 = *(const float4*)(src + 4);
    u16x8 o;
    o[0] = f2bf(v0.x); o[1] = f2bf(v0.y); o[2] = f2bf(v0.z); o[3] = f2bf(v0.w);
    o[4] = f2bf(v1.x); o[5] = f2bf(v1.y); o[6] = f2bf(v1.z); o[7] = f2bf(v1.w);
    *(u16x8*)&wcbf[(size_t)m * D_ + tile * 32 + g * 8] = o;
  } else {
    // --- repr: cap_repr[q][o] = Wred[o,:].cap0[q] + bred[o], wave-per-output ---
    const int b2 = bx - (B_ * RP_ + 512);             // 0..3071
    const int q = b2 >> 6, yo = b2 & 63;
    const int w = t >> 6, lane = t & 63;
    const int o = yo * 4 + w;   // 0..255
    const float4* c4 = (const float4*)(cap_embed + (size_t)q * 32 * D_);
    const float4* wr = (const float4*)(Wred + (size_t)o * D_);
    float acc = 0.f;
    #pragma unroll
    for (int j = 0; j < 4; j++) {
      float4 a = wr[lane + j*64], c = c4[lane + j*64];
      acc += a.x*c.x + a.y*c.y + a.z*c.z + a.w*c.w;
    }
    #pragma unroll
    for (int off = 32; off > 0; off >>= 1) acc += __shfl_down(acc, off);
    if (lane == 0) repr[(size_t)q * DQ_ + o] = acc + bred[o];
  }
}

// ---------------- k_wdyn: logits (3 per d) + K=3 softmax -> wpl planes [q][k][d] --------
// wave-per-d: grid (Q, 256), 4 waves/block
__global__ __launch_bounds__(256) void k_wdyn(const float* __restrict__ repr,
    const float* __restrict__ Wproj, const float* __restrict__ bproj,
    float* __restrict__ wpl)
{
  const int q = blockIdx.x;
  const int w = threadIdx.x >> 6, lane = threadIdx.x & 63;
  const int d = blockIdx.y * 4 + w;   // 0..1023
  float4 r4 = ((const float4*)(repr + (size_t)q * DQ_))[lane];
  float a0, a1, a2;
  {
    const float4* p0 = (const float4*)(Wproj + (size_t)(d*3 + 0) * DQ_);
    const float4* p1 = (const float4*)(Wproj + (size_t)(d*3 + 1) * DQ_);
    const float4* p2 = (const float4*)(Wproj + (size_t)(d*3 + 2) * DQ_);
    float4 v0 = p0[lane], v1 = p1[lane], v2 = p2[lane];
    a0 = v0.x*r4.x + v0.y*r4.y + v0.z*r4.z + v0.w*r4.w;
    a1 = v1.x*r4.x + v1.y*r4.y + v1.z*r4.z + v1.w*r4.w;
    a2 = v2.x*r4.x + v2.y*r4.y + v2.z*r4.z + v2.w*r4.w;
  }
  #pragma unroll
  for (int off = 32; off > 0; off >>= 1) {
    a0 += __shfl_down(a0, off);
    a1 += __shfl_down(a1, off);
    a2 += __shfl_down(a2, off);
  }
  if (lane == 0) {
    float l0 = a0 + bproj[d*3], l1 = a1 + bproj[d*3+1], l2 = a2 + bproj[d*3+2];
    float m = fmaxf(l0, fmaxf(l1, l2));
    float e0 = __expf(l0-m), e1 = __expf(l1-m), e2 = __expf(l2-m);
    float inv = 1.0f / (e0 + e1 + e2);
    wpl[((size_t)q*3 + 0) * D_ + d] = e0 * inv;
    wpl[((size_t)q*3 + 1) * D_ + d] = e1 * inv;
    wpl[((size_t)q*3 + 2) * D_ + d] = e2 * inv;
  }
}

// ---------------- k_cd: conv_dyn bf16 [ql][n=b*36+r][c], swizzled k-groups --------------
__global__ __launch_bounds__(256) void k_cd(const unsigned short* __restrict__ xpb,
    const float* __restrict__ wpl, unsigned short* __restrict__ cd, int qstart)
{
  const int ql = blockIdx.y, qg = qstart + ql;
  const int t = threadIdx.x;
  const int bloc = t >> 7;                  // 0..1
  const int b = blockIdx.x * 2 + bloc;
  const int gg = t & 127;                   // group-of-8 channels
  const int tile = gg >> 2, g = gg & 3;
  const int ch = gg * 8;

  float w0[8], w1[8], w2[8];
  {
    const float4* p0 = (const float4*)(wpl + ((size_t)qg*3 + 0)*D_ + ch);
    const float4* p1 = (const float4*)(wpl + ((size_t)qg*3 + 1)*D_ + ch);
    const float4* p2 = (const float4*)(wpl + ((size_t)qg*3 + 2)*D_ + ch);
    float4 a0 = p0[0], a1 = p0[1], b0 = p1[0], b1 = p1[1], d0 = p2[0], d1 = p2[1];
    w0[0]=a0.x; w0[1]=a0.y; w0[2]=a0.z; w0[3]=a0.w; w0[4]=a1.x; w0[5]=a1.y; w0[6]=a1.z; w0[7]=a1.w;
    w1[0]=b0.x; w1[1]=b0.y; w1[2]=b0.z; w1[3]=b0.w; w1[4]=b1.x; w1[5]=b1.y; w1[6]=b1.z; w1[7]=b1.w;
    w2[0]=d0.x; w2[1]=d0.y; w2[2]=d0.z; w2[3]=d0.w; w2[4]=d1.x; w2[5]=d1.y; w2[6]=d1.z; w2[7]=d1.w;
  }
  const unsigned short* xb = xpb + (size_t)b * RP_ * D_ + ch;
  u16x8 ra = *(const u16x8*)&xb[0];
  u16x8 rb = *(const u16x8*)&xb[D_];
  unsigned short* outb = cd + ((size_t)ql * NPQ_ + (size_t)b * R_) * D_ + tile * 32;
  for (int r = 0; r < R_; r++) {
    u16x8 rc = *(const u16x8*)&xb[(size_t)(r + 2) * D_];
    u16x8 o;
    #pragma unroll
    for (int i = 0; i < 8; i++) {
      float y = w0[i]*bf2f(ra[i]) + w1[i]*bf2f(rb[i]) + w2[i]*bf2f(rc[i]);
      o[i] = f2bf(y);
    }
    int gp = g ^ (((b * 36 + r) >> 1) & 3);
    *(u16x8*)&outb[(size_t)r * D_ + gp * 8] = o;
    ra = rb; rb = rc;
  }
}

// ---------------- k_gemm: Y = Wconv @ Cd_q, fused r-softmax epilogue -> imgvec ----------
// BM=256: 4 m-tiles/wave (frag-read amortization); ep[256][73] epilogue, 2 passes
#define BM_ 256
#define BN_ 144
#define BK_ 64

__global__ __launch_bounds__(256, 2) void k_gemm(
    const unsigned short* __restrict__ wcbf, const unsigned short* __restrict__ cd,
    const float* __restrict__ bconv, float* __restrict__ imgvec, int qstart)
{
  __shared__ __align__(16) unsigned char smem[74752];   // max(A 32KB + B 18KB, ep 256*73*4)
  unsigned short* As = (unsigned short*)smem;            // 32 quanta x 512 bf16 (chunk-major)
  unsigned short* Bs = (unsigned short*)(smem + 32768);  // 18 quanta x 512 bf16
  float* ep = (float*)smem;                              // [256][73] fp32 (epilogue)

  const int t = threadIdx.x;
  const int w = t >> 6, lane = t & 63;
  const int nt0 = blockIdx.x * BN_;
  const int dt0 = blockIdx.y * BM_;
  const int ql = blockIdx.z, qg = qstart + ql;

  f32x4 acc[4][9];
  #pragma unroll
  for (int mm = 0; mm < 4; mm++)
    #pragma unroll
    for (int nt = 0; nt < 9; nt++)
      acc[mm][nt] = (f32x4){0.f, 0.f, 0.f, 0.f};

  const int lrow = lane >> 2;          // 0..15 (row within 16-row chunk)
  const int lc8  = (lane & 3) * 8;     // 0,8,16,24 (phys k offset within 32-tile)
  const unsigned short* Ag = wcbf + (size_t)dt0 * D_ + lc8;
  const unsigned short* Bg = cd + ((size_t)ql * NPQ_ + nt0) * D_ + lc8;
  const int fr = lane & 15;
  // swizzled fragment offset within a 16x32 chunk (shorts):
  const int fro = fr * 32 + ((((lane >> 4) ^ ((fr >> 1) & 3))) << 3);

  for (int k0 = 0; k0 < D_; k0 += BK_) {
    #pragma unroll
    for (int jj = 0; jj < 8; jj++) {             // A: 16 row-chunks x 2 k-halves = 32 quanta
      int u = w + jj * 4;                        // u = ja*2 + h
      int ja = u >> 1, h = u & 1;
      gload_lds16(Ag + (size_t)(ja*16 + lrow) * D_ + k0 + h*32, As + u * 512);
    }
    for (int u = w; u < 18; u += 4) {            // B: 9 row-chunks x 2 k-halves
      int jb = u >> 1, h = u & 1;
      gload_lds16(Bg + (size_t)(jb*16 + lrow) * D_ + k0 + h*32, Bs + u * 512);
    }
    __syncthreads();
    #pragma unroll
    for (int s = 0; s < 2; s++) {
      bf16x8 aF[4], bF[9];
      #pragma unroll
      for (int mm = 0; mm < 4; mm++)
        aF[mm] = *(const bf16x8*)&As[((w*4 + mm)*2 + s) * 512 + fro];
      #pragma unroll
      for (int nt = 0; nt < 9; nt++)
        bF[nt] = *(const bf16x8*)&Bs[(nt*2 + s) * 512 + fro];
      #pragma unroll
      for (int mm = 0; mm < 4; mm++)
        #pragma unroll
        for (int nt = 0; nt < 9; nt++)
          acc[mm][nt] = __builtin_amdgcn_mfma_f32_16x16x32_bf16(aF[mm], bF[nt], acc[mm][nt], 0, 0, 0);
    }
    __syncthreads();
  }

  // Epilogue: softmax over r (36 cols per b). 2 col-passes (p), ep[256][73] fp32:
  // all 4 waves scatter their full 64-row range at once; each thread then handles
  // (dloc = t, bloc = 0,1) softmax rows. Pitch 73 -> 2-way LDS aliasing (free).
  const int quad = lane >> 4;
  const int b0 = nt0 / R_;   // first image-batch index of this tile (4 b's per tile)
  #pragma unroll
  for (int p = 0; p < 2; p++) {
    #pragma unroll
    for (int mm = 0; mm < 4; mm++)
      #pragma unroll
      for (int nt = 0; nt < 9; nt++) {
        int col = nt * 16 + fr;
        int cl = col - 72 * p;
        if (cl >= 0 && cl < 72) {
          #pragma unroll
          for (int rg = 0; rg < 4; rg++) {
            int rloc = w * 64 + mm * 16 + quad * 4 + rg;  // 0..255
            ep[rloc * 73 + cl] = acc[mm][nt][rg];
          }
        }
      }
    __syncthreads();
    #pragma unroll
    for (int bloc = 0; bloc < 2; bloc++) {
      int bg = b0 + p * 2 + bloc;
      int dg = dt0 + t;
      const float* yr = ep + t * 73 + bloc * 36;
      float m = yr[0];
      for (int r = 1; r < R_; r++) m = fmaxf(m, yr[r]);
      float s = 0.f, wsum = 0.f;
      for (int r = 0; r < R_; r++) {
        float yv = yr[r];
        float e = __expf(yv - m);
        s += e; wsum += e * yv;
      }
      // bconv[d] constant over r: softmax mask unchanged, add after weighted sum
      float img = wsum / s + bconv[dg];
      imgvec[((size_t)qg * B_ + bg) * D_ + dg] = img;
    }
    __syncthreads();
  }
}

// ---------------- k_sims: l2norm(img) . l2norm(cap0) -> out[b][q] ----------------
__global__ __launch_bounds__(256) void k_sims(const float* __restrict__ imgvec,
    const float* __restrict__ cap_embed, float* __restrict__ out)
{
  const int q = blockIdx.x, b = blockIdx.y, t = threadIdx.x;
  const float4* iv = (const float4*)(imgvec + ((size_t)q * B_ + b) * D_);
  const float4* cv = (const float4*)(cap_embed + (size_t)q * 32 * D_);  // token 0
  float4 a = iv[t], c = cv[t];
  float ss = a.x*a.x + a.y*a.y + a.z*a.z + a.w*a.w;
  float sc = c.x*c.x + c.y*c.y + c.z*c.z + c.w*c.w;
  float dt = a.x*c.x + a.y*c.y + a.z*c.z + a.w*c.w;
  #pragma unroll
  for (int off = 32; off > 0; off >>= 1) {
    ss += __shfl_down(ss, off);
    sc += __shfl_down(sc, off);
    dt += __shfl_down(dt, off);
  }
  __shared__ float r1[4], r2[4], r3[4];
  if ((t & 63) == 0) { r1[t >> 6] = ss; r2[t >> 6] = sc; r3[t >> 6] = dt; }
  __syncthreads();
  if (t == 0) {
    ss = r1[0] + r1[1] + r1[2] + r1[3];
    sc = r2[0] + r2[1] + r2[2] + r2[3];
    dt = r3[0] + r3[1] + r3[2] + r3[3];
    out[(size_t)b * Q_ + q] = dt * rsqrtf(ss) * rsqrtf(sc);
  }
}

extern "C" void kernel_launch(void* const* d_in, const int* in_sizes, int n_in,
                              void* d_out, int out_size, void* d_ws, size_t ws_size,
                              hipStream_t stream)
{
  (void)in_sizes; (void)n_in; (void)out_size;
  const float* img   = (const float*)d_in[0];
  const float* cap   = (const float*)d_in[1];
  // d_in[2] = lens : unused by the reference
  const float* Wred  = (const float*)d_in[3];
  const float* bred  = (const float*)d_in[4];
  const float* Wproj = (const float*)d_in[5];
  const float* bproj = (const float*)d_in[6];
  const float* Wconv = (const float*)d_in[7];
  const float* bconv = (const float*)d_in[8];
  float* out = (float*)d_out;

  char* ws = (char*)d_ws;
  const size_t XPB_B  = (size_t)B_ * RP_ * D_ * 2;       // 3,735,552
  const size_t WCBF_B = (size_t)D_ * D_ * 2;             // 2,097,152
  const size_t WPL_B  = (size_t)Q_ * 3 * D_ * 4;         //   589,824
  const size_t REPR_B = (size_t)Q_ * DQ_ * 4;            //    49,152
  const size_t IMGV_B = (size_t)Q_ * B_ * D_ * 4;        // 9,437,184
  unsigned short* xpb  = (unsigned short*)ws;
  unsigned short* wcbf = (unsigned short*)(ws + XPB_B);
  float* wpl    = (float*)(ws + XPB_B + WCBF_B);
  float* repr   = (float*)(ws + XPB_B + WCBF_B + WPL_B);
  float* imgvec = (float*)(ws + XPB_B + WCBF_B + WPL_B + REPR_B);
  const size_t FIXED = XPB_B + WCBF_B + WPL_B + REPR_B + IMGV_B;
  unsigned short* cdbuf = (unsigned short*)(ws + FIXED);
  const size_t PERQ = (size_t)NPQ_ * D_ * 2;             // 3,538,944 per q

  int qchunk = 1;
  if (ws_size > FIXED + PERQ) {
    size_t c = (ws_size - FIXED) / PERQ;
    qchunk = (c > (size_t)Q_) ? Q_ : (int)c;
  }

  k_pre<<<dim3(B_ * RP_ + 512 + Q_ * 64), dim3(256), 0, stream>>>(
      img, xpb, Wconv, wcbf, cap, Wred, bred, repr);
  k_wdyn<<<dim3(Q_, 256), dim3(256), 0, stream>>>(repr, Wproj, bproj, wpl);
  for (int q0 = 0; q0 < Q_; q0 += qchunk) {
    int qs = (Q_ - q0 < qchunk) ? (Q_ - q0) : qchunk;
    k_cd<<<dim3(B_ / 2, qs), dim3(256), 0, stream>>>(xpb, wpl, cdbuf, q0);
    k_gemm<<<dim3(NPQ_ / BN_, D_ / BM_, qs), dim3(256), 0, stream>>>(wcbf, cdbuf, bconv, imgvec, q0);
  }
  k_sims<<<dim3(Q_, B_), dim3(256), 0, stream>>>(imgvec, cap, out);
}